// Round 8
// baseline (787.323 us; speedup 1.0000x reference)
//
#include <hip/hip_runtime.h>
#include <math.h>

// Problem constants (from reference)
#define NN 5000
#define NNP 5120    // padded rows for GEMM A-operand OOB staging
#define NE 50000
#define NEE 55000   // edges + self loops
#define NG 8
#define NH 4

typedef __attribute__((ext_vector_type(8))) _Float16 half8;
typedef __attribute__((ext_vector_type(4))) _Float16 half4;
typedef __attribute__((ext_vector_type(4))) float floatx4;

// ---------------- utility device functions ----------------

__device__ inline float waveSum(float v) {
    #pragma unroll
    for (int o = 32; o > 0; o >>= 1) v += __shfl_xor(v, o, 64);
    return v;
}
__device__ inline float waveMax(float v) {
    #pragma unroll
    for (int o = 32; o > 0; o >>= 1) v = fmaxf(v, __shfl_xor(v, o, 64));
    return v;
}

// async global->LDS DMA, 16B per lane; lds dest is wave-uniform base + lane*16
__device__ __forceinline__ void gload_lds16(const _Float16* g, _Float16* l) {
    __builtin_amdgcn_global_load_lds(
        (__attribute__((address_space(1))) void*)g,
        (__attribute__((address_space(3))) void*)l,
        16, 0, 0);
}

// ---------------- fp32 -> fp16 conversion ----------------

__global__ void k_cvtA(const float* __restrict__ X, _Float16* __restrict__ A0, int n) {
    int i = blockIdx.x * 256 + threadIdx.x;
    if (i >= n) return;
    A0[i] = (_Float16)X[i];
}

// W (K x M fp32) -> B0 fp16 TRANSPOSED to (M x K)
__global__ __launch_bounds__(256) void k_cvtWT(const float* __restrict__ W,
        _Float16* __restrict__ B0, int K, int M)
{
    __shared__ float tile[32][33];
    int m0 = blockIdx.x * 32, k0 = blockIdx.y * 32;
    int tx = threadIdx.x & 31, ty = threadIdx.x >> 5;
    #pragma unroll
    for (int i = 0; i < 4; ++i)
        tile[ty + 8 * i][tx] = W[(size_t)(k0 + ty + 8 * i) * M + m0 + tx];
    __syncthreads();
    #pragma unroll
    for (int i = 0; i < 4; ++i) {
        int mm = ty + 8 * i, kk = tx;
        B0[(size_t)(m0 + mm) * K + kk + k0] = (_Float16)tile[kk][mm];
    }
}

// ---------------- MFMA fp16 GEMM, 128x256 tile, dbuf global_load_lds --------
// C(Mrows x N) = A @ Bcat^T + [biasL|biasR]; A fp16 (padded rows x K),
// Bcat fp16 (N x K) where N = 2*HC (Wl^T rows then Wr^T rows). Output fp16.
// 128x256x32 tile, 4 waves, wave tile 64x128, acc 4x8 floatx4 (128 VGPR).
// Intensity: 128 MFMA per 24 KB staged (85 FLOP/B vs 64 for 128x128).
__global__ __launch_bounds__(256, 2) void gemm_mfma_f16(
    const _Float16* __restrict__ A0, const _Float16* __restrict__ B0,
    const float* __restrict__ biasL, const float* __restrict__ biasR, int HC,
    _Float16* __restrict__ C, int Mrows, int K, int N)
{
    __shared__ __align__(16) _Float16 As[2][128 * 32];
    __shared__ __align__(16) _Float16 Bs[2][256 * 32];

    const int tid = threadIdx.x;
    const int wave = tid >> 6;
    const int lane = tid & 63;
    const int wm = (wave >> 1) * 64;    // wave row offset (2 row-waves)
    const int wn = (wave & 1) * 128;    // wave col offset (2 col-waves)
    const int lm = lane & 15;
    const int kq = (lane >> 4) * 8;
    const int rowBase = blockIdx.y * 128;
    const int colBase = blockIdx.x * 256;

    floatx4 acc[4][8];
    #pragma unroll
    for (int i = 0; i < 4; ++i)
        #pragma unroll
        for (int j = 0; j < 8; ++j)
            acc[i][j] = (floatx4){0.f, 0.f, 0.f, 0.f};

    // staging: wave owns A rows [w*32,+32) (2 issues), B rows [w*64,+64) (4)
    const int sr = lane >> 2;
    const int scol = (lane & 3) * 8;
    const _Float16* gA = A0 + (size_t)(rowBase + wave * 32 + sr) * K + scol;
    const _Float16* gB = B0 + (size_t)(colBase + wave * 64 + sr) * K + scol;
    const size_t skip16 = (size_t)16 * K;
    const int loA = (wave * 32) * 32;
    const int loB = (wave * 64) * 32;

    const int nk = K >> 5;
    // prologue
    {
        gload_lds16(gA, &As[0][loA]);
        gload_lds16(gA + skip16, &As[0][loA + 16 * 32]);
        gload_lds16(gB, &Bs[0][loB]);
        gload_lds16(gB + skip16, &Bs[0][loB + 16 * 32]);
        gload_lds16(gB + 2 * skip16, &Bs[0][loB + 32 * 32]);
        gload_lds16(gB + 3 * skip16, &Bs[0][loB + 48 * 32]);
    }
    __syncthreads();

    for (int t = 0; t < nk; ++t) {
        const int p = t & 1;
        if (t + 1 < nk) {
            const int k1 = (t + 1) << 5;
            gload_lds16(gA + k1, &As[p ^ 1][loA]);
            gload_lds16(gA + skip16 + k1, &As[p ^ 1][loA + 16 * 32]);
            gload_lds16(gB + k1, &Bs[p ^ 1][loB]);
            gload_lds16(gB + skip16 + k1, &Bs[p ^ 1][loB + 16 * 32]);
            gload_lds16(gB + 2 * skip16 + k1, &Bs[p ^ 1][loB + 32 * 32]);
            gload_lds16(gB + 3 * skip16 + k1, &Bs[p ^ 1][loB + 48 * 32]);
        }
        half8 a0[4], b0[8];
        #pragma unroll
        for (int i = 0; i < 4; ++i)
            a0[i] = *(const half8*)&As[p][(wm + i * 16 + lm) * 32 + kq];
        #pragma unroll
        for (int j = 0; j < 8; ++j)
            b0[j] = *(const half8*)&Bs[p][(wn + j * 16 + lm) * 32 + kq];
        #pragma unroll
        for (int i = 0; i < 4; ++i)
            #pragma unroll
            for (int j = 0; j < 8; ++j)
                acc[i][j] = __builtin_amdgcn_mfma_f32_16x16x32_f16(a0[i], b0[j], acc[i][j], 0, 0, 0);
        __syncthreads();
    }

    const int cq = (lane >> 4) * 4;
    #pragma unroll
    for (int j = 0; j < 8; ++j) {
        int col = colBase + wn + j * 16 + lm;
        float bv = (col < HC) ? biasL[col] : biasR[col - HC];
        #pragma unroll
        for (int i = 0; i < 4; ++i) {
            #pragma unroll
            for (int r = 0; r < 4; ++r) {
                int grow = rowBase + wm + i * 16 + cq + r;
                if (grow < Mrows)
                    C[(size_t)grow * N + col] = (_Float16)(acc[i][j][r] + bv);
            }
        }
    }
}

// ---------------- CSR build ----------------

__global__ void k_build_edges(const int* __restrict__ ei, int* __restrict__ src,
                              int* __restrict__ dst) {
    int i = blockIdx.x * 256 + threadIdx.x;
    if (i < NE) { src[i] = ei[i]; dst[i] = ei[NE + i]; }
    else if (i < NEE) { src[i] = i - NE; dst[i] = i - NE; }
}

__global__ void k_zero32(unsigned int* __restrict__ p, int n) {
    int i = blockIdx.x * 256 + threadIdx.x;
    if (i < n) p[i] = 0u;
}

__global__ void k_count(const int* __restrict__ dst, int* __restrict__ cnt) {
    int i = blockIdx.x * 256 + threadIdx.x;
    if (i < NEE) atomicAdd(&cnt[dst[i]], 1);
}

__global__ __launch_bounds__(256) void k_scan(const int* __restrict__ cnt,
                                              int* __restrict__ off, int* __restrict__ cur) {
    __shared__ int partial[256];
    __shared__ int ppre[257];
    int t = threadIdx.x;
    const int chunk = (NN + 255) / 256;
    int lo = t * chunk, hi = min(NN, (t + 1) * chunk);
    int s = 0;
    for (int i = lo; i < hi; ++i) s += cnt[i];
    partial[t] = s;
    __syncthreads();
    if (t == 0) {
        int acc = 0;
        for (int i = 0; i < 256; ++i) { ppre[i] = acc; acc += partial[i]; }
        ppre[256] = acc;
    }
    __syncthreads();
    int acc = ppre[t];
    for (int i = lo; i < hi; ++i) { off[i] = acc; cur[i] = acc; acc += cnt[i]; }
    if (t == 0) off[NN] = ppre[256];
}

__global__ void k_fill(const int* __restrict__ src, const int* __restrict__ dst,
                       int* __restrict__ cur, int* __restrict__ slist) {
    int e = blockIdx.x * 256 + threadIdx.x;
    if (e < NEE) { int p = atomicAdd(&cur[dst[e]], 1); slist[p] = src[e]; }
}

// ---------------- fused GATv2 edge pipeline (fp16, concat xcat) ------------
// xcat row n: [xl (4C halfs) | xr (4C halfs)], row stride 8C.
template<int C>
__global__ __launch_bounds__(256) void k_gat_fused(
    const _Float16* __restrict__ xcat,
    const float* __restrict__ att, const int* __restrict__ eoff,
    const int* __restrict__ slist, const float* __restrict__ bias,
    _Float16* __restrict__ out)
{
    constexpr int NQ = C / 256;          // float4 quads per lane per head
    __shared__ float red[NH * C];
    const int n = blockIdx.x;
    const int h = threadIdx.x >> 6;
    const int lane = threadIdx.x & 63;

    float4 xr_reg[NQ], att_reg[NQ], acc[NQ];
    {
        const _Float16* xrow = xcat + (size_t)n * (8 * C) + 4 * C + h * C;
        const float* ah = att + h * C;
        if constexpr (NQ >= 2) {
            #pragma unroll
            for (int q2 = 0; q2 < NQ / 2; ++q2) {
                int off = q2 * 512 + lane * 8;
                half8 hv = *(const half8*)(xrow + off);
                xr_reg[2 * q2]     = make_float4((float)hv[0], (float)hv[1], (float)hv[2], (float)hv[3]);
                xr_reg[2 * q2 + 1] = make_float4((float)hv[4], (float)hv[5], (float)hv[6], (float)hv[7]);
                att_reg[2 * q2]     = *(const float4*)(ah + off);
                att_reg[2 * q2 + 1] = *(const float4*)(ah + off + 4);
            }
        } else {
            int off = lane * 4;
            half4 hv = *(const half4*)(xrow + off);
            xr_reg[0] = make_float4((float)hv[0], (float)hv[1], (float)hv[2], (float)hv[3]);
            att_reg[0] = *(const float4*)(ah + off);
        }
        #pragma unroll
        for (int q = 0; q < NQ; ++q) acc[q] = make_float4(0.f, 0.f, 0.f, 0.f);
    }
    float m = -INFINITY, den = 0.f;
    const int start = eoff[n], end = eoff[n + 1];

    for (int j = start; j < end; ++j) {
        int s = slist[j];
        const _Float16* xlr = xcat + (size_t)s * (8 * C) + h * C;
        float4 xv[NQ];
        float ps = 0.f;
        if constexpr (NQ >= 2) {
            #pragma unroll
            for (int q2 = 0; q2 < NQ / 2; ++q2) {
                int off = q2 * 512 + lane * 8;
                half8 hv = *(const half8*)(xlr + off);
                xv[2 * q2]     = make_float4((float)hv[0], (float)hv[1], (float)hv[2], (float)hv[3]);
                xv[2 * q2 + 1] = make_float4((float)hv[4], (float)hv[5], (float)hv[6], (float)hv[7]);
            }
        } else {
            half4 hv = *(const half4*)(xlr + lane * 4);
            xv[0] = make_float4((float)hv[0], (float)hv[1], (float)hv[2], (float)hv[3]);
        }
        #pragma unroll
        for (int q = 0; q < NQ; ++q) {
            float vx = xv[q].x + xr_reg[q].x;
            float vy = xv[q].y + xr_reg[q].y;
            float vz = xv[q].z + xr_reg[q].z;
            float vw = xv[q].w + xr_reg[q].w;
            vx = vx > 0.f ? vx : 0.2f * vx;
            vy = vy > 0.f ? vy : 0.2f * vy;
            vz = vz > 0.f ? vz : 0.2f * vz;
            vw = vw > 0.f ? vw : 0.2f * vw;
            ps = fmaf(vx, att_reg[q].x, ps);
            ps = fmaf(vy, att_reg[q].y, ps);
            ps = fmaf(vz, att_reg[q].z, ps);
            ps = fmaf(vw, att_reg[q].w, ps);
        }
        ps = waveSum(ps);
        if (ps <= m) {                       // common case: max unchanged (wave-uniform)
            float ex = expf(ps - m);
            den += ex;
            #pragma unroll
            for (int q = 0; q < NQ; ++q) {
                acc[q].x = fmaf(ex, xv[q].x, acc[q].x);
                acc[q].y = fmaf(ex, xv[q].y, acc[q].y);
                acc[q].z = fmaf(ex, xv[q].z, acc[q].z);
                acc[q].w = fmaf(ex, xv[q].w, acc[q].w);
            }
        } else {                             // new max: rescale (ex == 1)
            float scale = expf(m - ps);      // first edge: exp(-inf)=0
            den = den * scale + 1.f;
            m = ps;
            #pragma unroll
            for (int q = 0; q < NQ; ++q) {
                acc[q].x = fmaf(acc[q].x, scale, xv[q].x);
                acc[q].y = fmaf(acc[q].y, scale, xv[q].y);
                acc[q].z = fmaf(acc[q].z, scale, xv[q].z);
                acc[q].w = fmaf(acc[q].w, scale, xv[q].w);
            }
        }
    }

    float inv = 1.f / (den + 1e-16f);
    if constexpr (NQ >= 2) {
        #pragma unroll
        for (int q2 = 0; q2 < NQ / 2; ++q2) {
            int off = q2 * 512 + lane * 8;
            float4 r0, r1;
            r0.x = acc[2*q2].x * inv;   r0.y = acc[2*q2].y * inv;
            r0.z = acc[2*q2].z * inv;   r0.w = acc[2*q2].w * inv;
            r1.x = acc[2*q2+1].x * inv; r1.y = acc[2*q2+1].y * inv;
            r1.z = acc[2*q2+1].z * inv; r1.w = acc[2*q2+1].w * inv;
            *(float4*)&red[h * C + off] = r0;
            *(float4*)&red[h * C + off + 4] = r1;
        }
    } else {
        int off = lane * 4;
        float4 r;
        r.x = acc[0].x * inv; r.y = acc[0].y * inv;
        r.z = acc[0].z * inv; r.w = acc[0].w * inv;
        *(float4*)&red[h * C + off] = r;
    }
    __syncthreads();

    int t = threadIdx.x;
    for (int c4 = t; c4 < C / 4; c4 += 256) {
        int c = c4 * 4;
        float4 r0 = *(const float4*)&red[0 * C + c];
        float4 r1 = *(const float4*)&red[1 * C + c];
        float4 r2 = *(const float4*)&red[2 * C + c];
        float4 r3 = *(const float4*)&red[3 * C + c];
        float4 bv = *(const float4*)(bias + c);
        half4 o;
        o[0] = (_Float16)fmaxf((r0.x + r1.x + r2.x + r3.x) * 0.25f + bv.x, 0.f);
        o[1] = (_Float16)fmaxf((r0.y + r1.y + r2.y + r3.y) * 0.25f + bv.y, 0.f);
        o[2] = (_Float16)fmaxf((r0.z + r1.z + r2.z + r3.z) * 0.25f + bv.z, 0.f);
        o[3] = (_Float16)fmaxf((r0.w + r1.w + r2.w + r3.w) * 0.25f + bv.w, 0.f);
        *(half4*)(out + (size_t)n * C + c) = o;
    }
}

// ---------------- gate + pool + MLP ----------------

__global__ __launch_bounds__(128) void k_gate(
    const _Float16* __restrict__ x, const float* __restrict__ Wg0,
    const float* __restrict__ bg0, const float* __restrict__ Wg1,
    const float* __restrict__ bg1, float* __restrict__ g)
{
    int n = blockIdx.x;
    int t = threadIdx.x;
    __shared__ float xs[256];
    __shared__ float wsum[2];
    const _Float16* xp = x + (size_t)n * 256;
    xs[t] = (float)xp[t]; xs[t + 128] = (float)xp[t + 128];
    __syncthreads();
    float acc = bg0[t];
    for (int k = 0; k < 256; ++k) acc = fmaf(xs[k], Wg0[k * 128 + t], acc);
    acc = acc > 0.f ? acc : 0.f;
    float prod = acc * Wg1[t];
    prod = waveSum(prod);
    if ((t & 63) == 0) wsum[t >> 6] = prod;
    __syncthreads();
    if (t == 0) g[n] = wsum[0] + wsum[1] + bg1[0];
}

__global__ void k_group_bounds(const int* __restrict__ batch, int* __restrict__ gstart,
                               int* __restrict__ gend) {
    int n = blockIdx.x * 256 + threadIdx.x;
    if (n >= NN) return;
    int b = batch[n];
    if (n == 0 || batch[n - 1] != b) gstart[b] = n;
    if (n == NN - 1 || batch[n + 1] != b) gend[b] = n + 1;
}

__global__ __launch_bounds__(256) void k_pool_stats(
    const float* __restrict__ g, const int* __restrict__ gstart,
    const int* __restrict__ gend, float* __restrict__ mOut,
    float* __restrict__ invdenOut)
{
    int gi = blockIdx.x;
    int t = threadIdx.x;
    int s0 = gstart[gi], e0 = gend[gi];
    __shared__ float red[4];
    float mx = -1e30f;
    for (int n = s0 + t; n < e0; n += 256) mx = fmaxf(mx, g[n]);
    float wm = waveMax(mx);
    if ((t & 63) == 0) red[t >> 6] = wm;
    __syncthreads();
    float m = fmaxf(fmaxf(red[0], red[1]), fmaxf(red[2], red[3]));
    __syncthreads();
    float sm = 0.f;
    for (int n = s0 + t; n < e0; n += 256) sm += expf(g[n] - m);
    sm = waveSum(sm);
    if ((t & 63) == 0) red[t >> 6] = sm;
    __syncthreads();
    if (t == 0) {
        float den = red[0] + red[1] + red[2] + red[3] + 1e-16f;
        mOut[gi] = m;
        invdenOut[gi] = 1.f / den;
    }
}

#define PCH 16
__global__ __launch_bounds__(256) void k_pool_acc(
    const _Float16* __restrict__ x, const float* __restrict__ g,
    const int* __restrict__ batch, const float* __restrict__ m,
    const float* __restrict__ invden, float* __restrict__ hpool)
{
    int base = blockIdx.x * PCH;
    int t = threadIdx.x;
    float acc = 0.f;
    int cur = -1;
    for (int i = 0; i < PCH; ++i) {
        int n = base + i;
        if (n >= NN) break;
        int b = batch[n];
        if (b != cur) {
            if (cur >= 0) atomicAdd(&hpool[cur * 256 + t], acc);
            cur = b; acc = 0.f;
        }
        float w = expf(g[n] - m[b]) * invden[b];
        acc = fmaf(w, (float)x[(size_t)n * 256 + t], acc);
    }
    if (cur >= 0) atomicAdd(&hpool[cur * 256 + t], acc);
}

__global__ __launch_bounds__(256) void k_mlp(
    const float* __restrict__ hpool,
    const float* __restrict__ Wm0, const float* __restrict__ bm0,
    const float* __restrict__ Wm1, const float* __restrict__ bm1,
    const float* __restrict__ Wm2, const float* __restrict__ bm2,
    const float* __restrict__ Wm3, const float* __restrict__ bm3,
    const float* __restrict__ Wm4, const float* __restrict__ bm4,
    float* __restrict__ out)
{
    __shared__ float bufA[8 * 256];
    __shared__ float bufB[8 * 128];
    int t = threadIdx.x;
    for (int i = t; i < 8 * 256; i += 256) bufA[i] = hpool[i];
    __syncthreads();
    for (int i = t; i < 8 * 128; i += 256) {
        int r = i >> 7, c = i & 127;
        float acc = bm0[c];
        for (int k = 0; k < 256; ++k) acc = fmaf(bufA[r * 256 + k], Wm0[k * 128 + c], acc);
        bufB[i] = fmaxf(acc, 0.f);
    }
    __syncthreads();
    for (int i = t; i < 8 * 64; i += 256) {
        int r = i >> 6, c = i & 63;
        float acc = bm1[c];
        for (int k = 0; k < 128; ++k) acc = fmaf(bufB[r * 128 + k], Wm1[k * 64 + c], acc);
        bufA[i] = fmaxf(acc, 0.f);
    }
    __syncthreads();
    for (int i = t; i < 8 * 32; i += 256) {
        int r = i >> 5, c = i & 31;
        float acc = bm2[c];
        for (int k = 0; k < 64; ++k) acc = fmaf(bufA[r * 64 + k], Wm2[k * 32 + c], acc);
        bufB[i] = fmaxf(acc, 0.f);
    }
    __syncthreads();
    for (int i = t; i < 8 * 16; i += 256) {
        int r = i >> 4, c = i & 15;
        float acc = bm3[c];
        for (int k = 0; k < 32; ++k) acc = fmaf(bufB[r * 32 + k], Wm3[k * 16 + c], acc);
        bufA[i] = fmaxf(acc, 0.f);
    }
    __syncthreads();
    if (t < 8) {
        float acc = bm4[0];
        for (int k = 0; k < 16; ++k) acc = fmaf(bufA[t * 16 + k], Wm4[k], acc);
        out[t] = acc;
    }
}

// ---------------- host orchestration ----------------

static void run_gat_layer(const _Float16* ain, int K, int C,
                          const float* Wl, const float* bl,
                          const float* Wr, const float* br,
                          const float* att, const float* bias,
                          _Float16* wbcat, _Float16* xcat,
                          const int* eoff, const int* slist,
                          _Float16* xout, hipStream_t stream)
{
    int HC = NH * C;
    dim3 tgrid(HC / 32, K / 32);
    k_cvtWT<<<tgrid, 256, 0, stream>>>(Wl, wbcat, K, HC);
    k_cvtWT<<<tgrid, 256, 0, stream>>>(Wr, wbcat + (size_t)HC * K, K, HC);
    dim3 ggrid((2 * HC) / 256, NNP / 128);
    gemm_mfma_f16<<<ggrid, 256, 0, stream>>>(ain, wbcat, bl, br, HC,
                                             xcat, NN, K, 2 * HC);

    if (C == 1024)
        k_gat_fused<1024><<<NN, 256, 0, stream>>>(xcat, att, eoff, slist, bias, xout);
    else if (C == 512)
        k_gat_fused<512><<<NN, 256, 0, stream>>>(xcat, att, eoff, slist, bias, xout);
    else
        k_gat_fused<256><<<NN, 256, 0, stream>>>(xcat, att, eoff, slist, bias, xout);
}

extern "C" void kernel_launch(void* const* d_in, const int* in_sizes, int n_in,
                              void* d_out, int out_size, void* d_ws, size_t ws_size,
                              hipStream_t stream) {
    const float* x      = (const float*)d_in[0];
    const int* ei       = (const int*)d_in[1];
    const int* batch    = (const int*)d_in[2];
    const float* Wl1 = (const float*)d_in[3];  const float* bl1 = (const float*)d_in[4];
    const float* Wr1 = (const float*)d_in[5];  const float* br1 = (const float*)d_in[6];
    const float* att1= (const float*)d_in[7];  const float* b1  = (const float*)d_in[8];
    const float* Wl2 = (const float*)d_in[9];  const float* bl2 = (const float*)d_in[10];
    const float* Wr2 = (const float*)d_in[11]; const float* br2 = (const float*)d_in[12];
    const float* att2= (const float*)d_in[13]; const float* b2  = (const float*)d_in[14];
    const float* Wl3 = (const float*)d_in[15]; const float* bl3 = (const float*)d_in[16];
    const float* Wr3 = (const float*)d_in[17]; const float* br3 = (const float*)d_in[18];
    const float* att3= (const float*)d_in[19]; const float* b3  = (const float*)d_in[20];
    const float* Wm0 = (const float*)d_in[21]; const float* bm0 = (const float*)d_in[22];
    const float* Wm1 = (const float*)d_in[23]; const float* bm1 = (const float*)d_in[24];
    const float* Wm2 = (const float*)d_in[25]; const float* bm2 = (const float*)d_in[26];
    const float* Wm3 = (const float*)d_in[27]; const float* bm3 = (const float*)d_in[28];
    const float* Wm4 = (const float*)d_in[29]; const float* bm4 = (const float*)d_in[30];
    const float* Wg0 = (const float*)d_in[31]; const float* bg0 = (const float*)d_in[32];
    const float* Wg1 = (const float*)d_in[33]; const float* bg1 = (const float*)d_in[34];
    float* out = (float*)d_out;

    // workspace carve (float units = 4B); fp16 buffers 16B-aligned
    float* ws = (float*)d_ws;
    size_t o = 0;
    _Float16* xcat = (_Float16*)(ws + o); o += (size_t)NNP * 8192 / 2;  // max 2HC
    _Float16* x1  = (_Float16*)(ws + o); o += (size_t)NNP * 1024 / 2;
    _Float16* x2  = (_Float16*)(ws + o); o += (size_t)NNP * 512 / 2;
    _Float16* x3  = (_Float16*)(ws + o); o += (size_t)NNP * 256 / 2;
    _Float16* a0p = (_Float16*)(ws + o); o += (size_t)NNP * 1536 / 2;
    _Float16* wbcat = (_Float16*)(ws + o); o += (size_t)2 * 1536 * 4096 / 2;
    int* srcA    = (int*)(ws + o); o += NEE;
    int* dstA    = (int*)(ws + o); o += NEE;
    int* cnt     = (int*)(ws + o); o += NN;
    int* eoff    = (int*)(ws + o); o += NN + 1;
    int* cur     = (int*)(ws + o); o += NN;
    int* slist   = (int*)(ws + o); o += NEE;
    float* g     = ws + o; o += NN;
    int* gstart  = (int*)(ws + o); o += NG;
    int* gend    = (int*)(ws + o); o += NG;
    float* gm    = ws + o; o += NG;
    float* ginv  = ws + o; o += NG;
    float* hpool = ws + o; o += NG * 256;

    // build CSR by dst (slist holds src node ids)
    int ebB = (NEE + 255) / 256;
    k_build_edges<<<ebB, 256, 0, stream>>>(ei, srcA, dstA);
    k_zero32<<<(NN + 255) / 256, 256, 0, stream>>>((unsigned int*)cnt, NN);
    k_count<<<ebB, 256, 0, stream>>>(dstA, cnt);
    k_scan<<<1, 256, 0, stream>>>(cnt, eoff, cur);
    k_fill<<<ebB, 256, 0, stream>>>(srcA, dstA, cur, slist);

    // layer-1 input -> fp16
    int nA = NN * 1536;
    k_cvtA<<<(nA + 255) / 256, 256, 0, stream>>>(x, a0p, nA);

    // three GATv2 layers
    run_gat_layer(a0p, 1536, 1024, Wl1, bl1, Wr1, br1, att1, b1,
                  wbcat, xcat, eoff, slist, x1, stream);
    run_gat_layer(x1,  1024, 512,  Wl2, bl2, Wr2, br2, att2, b2,
                  wbcat, xcat, eoff, slist, x2, stream);
    run_gat_layer(x2,  512,  256,  Wl3, bl3, Wr3, br3, att3, b3,
                  wbcat, xcat, eoff, slist, x3, stream);

    // gate + pool + MLP
    k_gate<<<NN, 128, 0, stream>>>(x3, Wg0, bg0, Wg1, bg1, g);
    k_zero32<<<1, 64, 0, stream>>>((unsigned int*)gstart, 2 * NG);
    k_group_bounds<<<(NN + 255) / 256, 256, 0, stream>>>(batch, gstart, gend);
    k_pool_stats<<<NG, 256, 0, stream>>>(g, gstart, gend, gm, ginv);
    k_zero32<<<(NG * 256 + 255) / 256, 256, 0, stream>>>((unsigned int*)hpool, NG * 256);
    k_pool_acc<<<(NN + PCH - 1) / PCH, 256, 0, stream>>>(x3, g, batch, gm, ginv, hpool);
    k_mlp<<<1, 256, 0, stream>>>(hpool, Wm0, bm0, Wm1, bm1, Wm2, bm2,
                                 Wm3, bm3, Wm4, bm4, out);
}

// Round 9
// 767.751 us; speedup vs baseline: 1.0255x; 1.0255x over previous
//
#include <hip/hip_runtime.h>
#include <math.h>

// Problem constants (from reference)
#define NN 5000
#define NNP 5120    // padded rows for GEMM A-operand OOB staging
#define NE 50000
#define NEE 55000   // edges + self loops
#define NG 8
#define NH 4

typedef __attribute__((ext_vector_type(8))) _Float16 half8;
typedef __attribute__((ext_vector_type(4))) _Float16 half4;
typedef __attribute__((ext_vector_type(4))) float floatx4;

// ---------------- utility device functions ----------------

__device__ inline float waveSum(float v) {
    #pragma unroll
    for (int o = 32; o > 0; o >>= 1) v += __shfl_xor(v, o, 64);
    return v;
}
__device__ inline float waveMax(float v) {
    #pragma unroll
    for (int o = 32; o > 0; o >>= 1) v = fmaxf(v, __shfl_xor(v, o, 64));
    return v;
}

// async global->LDS DMA, 16B per lane; lds dest is wave-uniform base + lane*16
__device__ __forceinline__ void gload_lds16(const _Float16* g, _Float16* l) {
    __builtin_amdgcn_global_load_lds(
        (__attribute__((address_space(1))) void*)g,
        (__attribute__((address_space(3))) void*)l,
        16, 0, 0);
}

// ---------------- fp32 -> fp16 conversion ----------------

__global__ void k_cvtA(const float* __restrict__ X, _Float16* __restrict__ A0, int n) {
    int i = blockIdx.x * 256 + threadIdx.x;
    if (i >= n) return;
    A0[i] = (_Float16)X[i];
}

// W (K x M fp32) -> B0 fp16 TRANSPOSED to (M x K)
__global__ __launch_bounds__(256) void k_cvtWT(const float* __restrict__ W,
        _Float16* __restrict__ B0, int K, int M)
{
    __shared__ float tile[32][33];
    int m0 = blockIdx.x * 32, k0 = blockIdx.y * 32;
    int tx = threadIdx.x & 31, ty = threadIdx.x >> 5;
    #pragma unroll
    for (int i = 0; i < 4; ++i)
        tile[ty + 8 * i][tx] = W[(size_t)(k0 + ty + 8 * i) * M + m0 + tx];
    __syncthreads();
    #pragma unroll
    for (int i = 0; i < 4; ++i) {
        int mm = ty + 8 * i, kk = tx;
        B0[(size_t)(m0 + mm) * K + kk + k0] = (_Float16)tile[kk][mm];
    }
}

// ---------------- MFMA fp16 GEMM, dbuf global_load_lds + XOR bank swizzle ----
// C(Mrows x N) = A @ B^T + bias; A fp16 (padded rows x K), B fp16 (N x K).
// Output fp16. LDS [128][32]-half rows (64 B) alias banks at half the 128 B
// period -> 8-way read conflicts (R6-R8: 2.9x LDS slowdown, measured-matched).
// Fix: XOR-swizzle which 16B chunk each lane stages: chunk position p holds
// global chunk p ^ ((row>>1)&3). Fragment reads apply the same XOR -> every
// bank hit exactly 2x per 16-lane phase (2-way = free, m136).
__global__ __launch_bounds__(256) void gemm_mfma_f16(
    const _Float16* __restrict__ A0, const _Float16* __restrict__ B0,
    const float* __restrict__ bias, _Float16* __restrict__ C,
    int Mrows, int K, int N)
{
    __shared__ __align__(16) _Float16 As[2][128 * 32];
    __shared__ __align__(16) _Float16 Bs[2][128 * 32];

    const int tid = threadIdx.x;
    const int wave = tid >> 6;
    const int lane = tid & 63;
    const int wm = (wave >> 1) * 64;
    const int wn = (wave & 1) * 64;
    const int lm = lane & 15;
    // swizzled chunk offset for fragment reads (halfs)
    const int swz = (((lane >> 4) ^ ((lane >> 1) & 3)) << 3);
    const int rowBase = blockIdx.y * 128;
    const int colBase = blockIdx.x * 128;

    floatx4 acc[4][4];
    #pragma unroll
    for (int i = 0; i < 4; ++i)
        #pragma unroll
        for (int j = 0; j < 4; ++j)
            acc[i][j] = (floatx4){0.f, 0.f, 0.f, 0.f};

    // staging: wave owns rows [w*32, w*32+32), 2 issues of 16 rows per matrix.
    // lane -> row (lane>>2), global chunk (lane&3)^((lane>>3)&3)  [the swizzle]
    const int sr = lane >> 2;
    const int scol = (((lane & 3) ^ ((lane >> 3) & 3)) << 3);
    const _Float16* gA = A0 + (size_t)(rowBase + wave * 32 + sr) * K + scol;
    const _Float16* gB = B0 + (size_t)(colBase + wave * 32 + sr) * K + scol;
    const size_t skip16 = (size_t)16 * K;
    const int lo0 = (wave * 32) * 32;
    const int lo1 = (wave * 32 + 16) * 32;

    // prologue: tile 0 -> buf 0
    gload_lds16(gA, &As[0][lo0]);
    gload_lds16(gA + skip16, &As[0][lo1]);
    gload_lds16(gB, &Bs[0][lo0]);
    gload_lds16(gB + skip16, &Bs[0][lo1]);
    __syncthreads();

    const int nk = K >> 5;
    for (int t = 0; t < nk; ++t) {
        const int p = t & 1;
        if (t + 1 < nk) {          // prefetch tile t+1 into the other buffer
            const int k1 = (t + 1) << 5;
            gload_lds16(gA + k1, &As[p ^ 1][lo0]);
            gload_lds16(gA + skip16 + k1, &As[p ^ 1][lo1]);
            gload_lds16(gB + k1, &Bs[p ^ 1][lo0]);
            gload_lds16(gB + skip16 + k1, &Bs[p ^ 1][lo1]);
        }
        half8 a0[4], b0[4];
        #pragma unroll
        for (int i = 0; i < 4; ++i) {
            a0[i] = *(const half8*)&As[p][(wm + i * 16 + lm) * 32 + swz];
            b0[i] = *(const half8*)&Bs[p][(wn + i * 16 + lm) * 32 + swz];
        }
        #pragma unroll
        for (int i = 0; i < 4; ++i)
            #pragma unroll
            for (int j = 0; j < 4; ++j)
                acc[i][j] = __builtin_amdgcn_mfma_f32_16x16x32_f16(a0[i], b0[j], acc[i][j], 0, 0, 0);
        __syncthreads();
    }

    const int cq = (lane >> 4) * 4;
    #pragma unroll
    for (int j = 0; j < 4; ++j) {
        int col = colBase + wn + j * 16 + lm;
        float bv = bias[col];
        #pragma unroll
        for (int i = 0; i < 4; ++i) {
            #pragma unroll
            for (int r = 0; r < 4; ++r) {
                int grow = rowBase + wm + i * 16 + cq + r;
                if (grow < Mrows)
                    C[(size_t)grow * N + col] = (_Float16)(acc[i][j][r] + bv);
            }
        }
    }
}

// ---------------- CSR build ----------------

__global__ void k_build_edges(const int* __restrict__ ei, int* __restrict__ src,
                              int* __restrict__ dst) {
    int i = blockIdx.x * 256 + threadIdx.x;
    if (i < NE) { src[i] = ei[i]; dst[i] = ei[NE + i]; }
    else if (i < NEE) { src[i] = i - NE; dst[i] = i - NE; }
}

__global__ void k_zero32(unsigned int* __restrict__ p, int n) {
    int i = blockIdx.x * 256 + threadIdx.x;
    if (i < n) p[i] = 0u;
}

__global__ void k_count(const int* __restrict__ dst, int* __restrict__ cnt) {
    int i = blockIdx.x * 256 + threadIdx.x;
    if (i < NEE) atomicAdd(&cnt[dst[i]], 1);
}

__global__ __launch_bounds__(256) void k_scan(const int* __restrict__ cnt,
                                              int* __restrict__ off, int* __restrict__ cur) {
    __shared__ int partial[256];
    __shared__ int ppre[257];
    int t = threadIdx.x;
    const int chunk = (NN + 255) / 256;
    int lo = t * chunk, hi = min(NN, (t + 1) * chunk);
    int s = 0;
    for (int i = lo; i < hi; ++i) s += cnt[i];
    partial[t] = s;
    __syncthreads();
    if (t == 0) {
        int acc = 0;
        for (int i = 0; i < 256; ++i) { ppre[i] = acc; acc += partial[i]; }
        ppre[256] = acc;
    }
    __syncthreads();
    int acc = ppre[t];
    for (int i = lo; i < hi; ++i) { off[i] = acc; cur[i] = acc; acc += cnt[i]; }
    if (t == 0) off[NN] = ppre[256];
}

__global__ void k_fill(const int* __restrict__ src, const int* __restrict__ dst,
                       int* __restrict__ cur, int* __restrict__ slist) {
    int e = blockIdx.x * 256 + threadIdx.x;
    if (e < NEE) { int p = atomicAdd(&cur[dst[e]], 1); slist[p] = src[e]; }
}

// ---------------- fused GATv2 edge pipeline (fp16 activations) -------------
template<int C>
__global__ __launch_bounds__(256) void k_gat_fused(
    const _Float16* __restrict__ xl, const _Float16* __restrict__ xr,
    const float* __restrict__ att, const int* __restrict__ eoff,
    const int* __restrict__ slist, const float* __restrict__ bias,
    _Float16* __restrict__ out)
{
    constexpr int NQ = C / 256;
    __shared__ float red[NH * C];
    const int n = blockIdx.x;
    const int h = threadIdx.x >> 6;
    const int lane = threadIdx.x & 63;

    float4 xr_reg[NQ], att_reg[NQ], acc[NQ];
    {
        const _Float16* xrow = xr + (size_t)n * (NH * C) + h * C;
        const float* ah   = att + h * C;
        #pragma unroll
        for (int q = 0; q < NQ; ++q) {
            int off = q * 256 + lane * 4;
            half4 hv = *(const half4*)(xrow + off);
            xr_reg[q] = make_float4((float)hv[0], (float)hv[1], (float)hv[2], (float)hv[3]);
            att_reg[q] = *(const float4*)(ah + off);
            acc[q] = make_float4(0.f, 0.f, 0.f, 0.f);
        }
    }
    float m = -INFINITY, den = 0.f;
    const int start = eoff[n], end = eoff[n + 1];

    for (int j = start; j < end; ++j) {
        int s = slist[j];
        const _Float16* xlr = xl + (size_t)s * (NH * C) + h * C;
        float4 xv[NQ];
        float ps = 0.f;
        #pragma unroll
        for (int q = 0; q < NQ; ++q) {
            half4 hv = *(const half4*)(xlr + q * 256 + lane * 4);
            xv[q] = make_float4((float)hv[0], (float)hv[1], (float)hv[2], (float)hv[3]);
            float vx = xv[q].x + xr_reg[q].x;
            float vy = xv[q].y + xr_reg[q].y;
            float vz = xv[q].z + xr_reg[q].z;
            float vw = xv[q].w + xr_reg[q].w;
            vx = vx > 0.f ? vx : 0.2f * vx;
            vy = vy > 0.f ? vy : 0.2f * vy;
            vz = vz > 0.f ? vz : 0.2f * vz;
            vw = vw > 0.f ? vw : 0.2f * vw;
            ps = fmaf(vx, att_reg[q].x, ps);
            ps = fmaf(vy, att_reg[q].y, ps);
            ps = fmaf(vz, att_reg[q].z, ps);
            ps = fmaf(vw, att_reg[q].w, ps);
        }
        ps = waveSum(ps);
        float m_new = fmaxf(m, ps);
        float scale = expf(m - m_new);
        float ex = expf(ps - m_new);
        den = den * scale + ex;
        m = m_new;
        #pragma unroll
        for (int q = 0; q < NQ; ++q) {
            acc[q].x = fmaf(ex, xv[q].x, acc[q].x * scale);
            acc[q].y = fmaf(ex, xv[q].y, acc[q].y * scale);
            acc[q].z = fmaf(ex, xv[q].z, acc[q].z * scale);
            acc[q].w = fmaf(ex, xv[q].w, acc[q].w * scale);
        }
    }

    float inv = 1.f / (den + 1e-16f);
    #pragma unroll
    for (int q = 0; q < NQ; ++q) {
        int off = q * 256 + lane * 4;
        float4 r;
        r.x = acc[q].x * inv; r.y = acc[q].y * inv;
        r.z = acc[q].z * inv; r.w = acc[q].w * inv;
        *(float4*)&red[h * C + off] = r;
    }
    __syncthreads();

    int t = threadIdx.x;
    for (int c4 = t; c4 < C / 4; c4 += 256) {
        int c = c4 * 4;
        float4 r0 = *(const float4*)&red[0 * C + c];
        float4 r1 = *(const float4*)&red[1 * C + c];
        float4 r2 = *(const float4*)&red[2 * C + c];
        float4 r3 = *(const float4*)&red[3 * C + c];
        float4 bv = *(const float4*)(bias + c);
        half4 o;
        o[0] = (_Float16)fmaxf((r0.x + r1.x + r2.x + r3.x) * 0.25f + bv.x, 0.f);
        o[1] = (_Float16)fmaxf((r0.y + r1.y + r2.y + r3.y) * 0.25f + bv.y, 0.f);
        o[2] = (_Float16)fmaxf((r0.z + r1.z + r2.z + r3.z) * 0.25f + bv.z, 0.f);
        o[3] = (_Float16)fmaxf((r0.w + r1.w + r2.w + r3.w) * 0.25f + bv.w, 0.f);
        *(half4*)(out + (size_t)n * C + c) = o;
    }
}

// ---------------- gate + pool + MLP ----------------

__global__ __launch_bounds__(128) void k_gate(
    const _Float16* __restrict__ x, const float* __restrict__ Wg0,
    const float* __restrict__ bg0, const float* __restrict__ Wg1,
    const float* __restrict__ bg1, float* __restrict__ g)
{
    int n = blockIdx.x;
    int t = threadIdx.x;
    __shared__ float xs[256];
    __shared__ float wsum[2];
    const _Float16* xp = x + (size_t)n * 256;
    xs[t] = (float)xp[t]; xs[t + 128] = (float)xp[t + 128];
    __syncthreads();
    float acc = bg0[t];
    for (int k = 0; k < 256; ++k) acc = fmaf(xs[k], Wg0[k * 128 + t], acc);
    acc = acc > 0.f ? acc : 0.f;
    float prod = acc * Wg1[t];
    prod = waveSum(prod);
    if ((t & 63) == 0) wsum[t >> 6] = prod;
    __syncthreads();
    if (t == 0) g[n] = wsum[0] + wsum[1] + bg1[0];
}

__global__ void k_group_bounds(const int* __restrict__ batch, int* __restrict__ gstart,
                               int* __restrict__ gend) {
    int n = blockIdx.x * 256 + threadIdx.x;
    if (n >= NN) return;
    int b = batch[n];
    if (n == 0 || batch[n - 1] != b) gstart[b] = n;
    if (n == NN - 1 || batch[n + 1] != b) gend[b] = n + 1;
}

// per-group softmax stats: m[g], invden[g]
__global__ __launch_bounds__(256) void k_pool_stats(
    const float* __restrict__ g, const int* __restrict__ gstart,
    const int* __restrict__ gend, float* __restrict__ mOut,
    float* __restrict__ invdenOut)
{
    int gi = blockIdx.x;
    int t = threadIdx.x;
    int s0 = gstart[gi], e0 = gend[gi];
    __shared__ float red[4];
    float mx = -1e30f;
    for (int n = s0 + t; n < e0; n += 256) mx = fmaxf(mx, g[n]);
    float wm = waveMax(mx);
    if ((t & 63) == 0) red[t >> 6] = wm;
    __syncthreads();
    float m = fmaxf(fmaxf(red[0], red[1]), fmaxf(red[2], red[3]));
    __syncthreads();
    float sm = 0.f;
    for (int n = s0 + t; n < e0; n += 256) sm += expf(g[n] - m);
    sm = waveSum(sm);
    if ((t & 63) == 0) red[t >> 6] = sm;
    __syncthreads();
    if (t == 0) {
        float den = red[0] + red[1] + red[2] + red[3] + 1e-16f;
        mOut[gi] = m;
        invdenOut[gi] = 1.f / den;
    }
}

#define PCH 16
__global__ __launch_bounds__(256) void k_pool_acc(
    const _Float16* __restrict__ x, const float* __restrict__ g,
    const int* __restrict__ batch, const float* __restrict__ m,
    const float* __restrict__ invden, float* __restrict__ hpool)
{
    int base = blockIdx.x * PCH;
    int t = threadIdx.x;
    float acc = 0.f;
    int cur = -1;
    for (int i = 0; i < PCH; ++i) {
        int n = base + i;
        if (n >= NN) break;
        int b = batch[n];
        if (b != cur) {
            if (cur >= 0) atomicAdd(&hpool[cur * 256 + t], acc);
            cur = b; acc = 0.f;
        }
        float w = expf(g[n] - m[b]) * invden[b];
        acc = fmaf(w, (float)x[(size_t)n * 256 + t], acc);
    }
    if (cur >= 0) atomicAdd(&hpool[cur * 256 + t], acc);
}

__global__ __launch_bounds__(256) void k_mlp(
    const float* __restrict__ hpool,
    const float* __restrict__ Wm0, const float* __restrict__ bm0,
    const float* __restrict__ Wm1, const float* __restrict__ bm1,
    const float* __restrict__ Wm2, const float* __restrict__ bm2,
    const float* __restrict__ Wm3, const float* __restrict__ bm3,
    const float* __restrict__ Wm4, const float* __restrict__ bm4,
    float* __restrict__ out)
{
    __shared__ float bufA[8 * 256];
    __shared__ float bufB[8 * 128];
    int t = threadIdx.x;
    for (int i = t; i < 8 * 256; i += 256) bufA[i] = hpool[i];
    __syncthreads();
    for (int i = t; i < 8 * 128; i += 256) {
        int r = i >> 7, c = i & 127;
        float acc = bm0[c];
        for (int k = 0; k < 256; ++k) acc = fmaf(bufA[r * 256 + k], Wm0[k * 128 + c], acc);
        bufB[i] = fmaxf(acc, 0.f);
    }
    __syncthreads();
    for (int i = t; i < 8 * 64; i += 256) {
        int r = i >> 6, c = i & 63;
        float acc = bm1[c];
        for (int k = 0; k < 128; ++k) acc = fmaf(bufB[r * 128 + k], Wm1[k * 64 + c], acc);
        bufA[i] = fmaxf(acc, 0.f);
    }
    __syncthreads();
    for (int i = t; i < 8 * 32; i += 256) {
        int r = i >> 5, c = i & 31;
        float acc = bm2[c];
        for (int k = 0; k < 64; ++k) acc = fmaf(bufA[r * 64 + k], Wm2[k * 32 + c], acc);
        bufB[i] = fmaxf(acc, 0.f);
    }
    __syncthreads();
    for (int i = t; i < 8 * 16; i += 256) {
        int r = i >> 4, c = i & 15;
        float acc = bm3[c];
        for (int k = 0; k < 32; ++k) acc = fmaf(bufB[r * 32 + k], Wm3[k * 16 + c], acc);
        bufA[i] = fmaxf(acc, 0.f);
    }
    __syncthreads();
    if (t < 8) {
        float acc = bm4[0];
        for (int k = 0; k < 16; ++k) acc = fmaf(bufA[t * 16 + k], Wm4[k], acc);
        out[t] = acc;
    }
}

// ---------------- host orchestration ----------------

static void run_gat_layer(const _Float16* ain, int K, int C,
                          const float* Wl, const float* bl,
                          const float* Wr, const float* br,
                          const float* att, const float* bias,
                          _Float16* wb0, _Float16* xl, _Float16* xr,
                          const int* eoff, const int* slist,
                          _Float16* xout, hipStream_t stream)
{
    int HC = NH * C;
    dim3 ggrid(HC / 128, NNP / 128);
    dim3 tgrid(HC / 32, K / 32);
    k_cvtWT<<<tgrid, 256, 0, stream>>>(Wl, wb0, K, HC);
    gemm_mfma_f16<<<ggrid, 256, 0, stream>>>(ain, wb0, bl, xl, NN, K, HC);
    k_cvtWT<<<tgrid, 256, 0, stream>>>(Wr, wb0, K, HC);
    gemm_mfma_f16<<<ggrid, 256, 0, stream>>>(ain, wb0, br, xr, NN, K, HC);

    if (C == 1024)
        k_gat_fused<1024><<<NN, 256, 0, stream>>>(xl, xr, att, eoff, slist, bias, xout);
    else if (C == 512)
        k_gat_fused<512><<<NN, 256, 0, stream>>>(xl, xr, att, eoff, slist, bias, xout);
    else
        k_gat_fused<256><<<NN, 256, 0, stream>>>(xl, xr, att, eoff, slist, bias, xout);
}

extern "C" void kernel_launch(void* const* d_in, const int* in_sizes, int n_in,
                              void* d_out, int out_size, void* d_ws, size_t ws_size,
                              hipStream_t stream) {
    const float* x      = (const float*)d_in[0];
    const int* ei       = (const int*)d_in[1];
    const int* batch    = (const int*)d_in[2];
    const float* Wl1 = (const float*)d_in[3];  const float* bl1 = (const float*)d_in[4];
    const float* Wr1 = (const float*)d_in[5];  const float* br1 = (const float*)d_in[6];
    const float* att1= (const float*)d_in[7];  const float* b1  = (const float*)d_in[8];
    const float* Wl2 = (const float*)d_in[9];  const float* bl2 = (const float*)d_in[10];
    const float* Wr2 = (const float*)d_in[11]; const float* br2 = (const float*)d_in[12];
    const float* att2= (const float*)d_in[13]; const float* b2  = (const float*)d_in[14];
    const float* Wl3 = (const float*)d_in[15]; const float* bl3 = (const float*)d_in[16];
    const float* Wr3 = (const float*)d_in[17]; const float* br3 = (const float*)d_in[18];
    const float* att3= (const float*)d_in[19]; const float* b3  = (const float*)d_in[20];
    const float* Wm0 = (const float*)d_in[21]; const float* bm0 = (const float*)d_in[22];
    const float* Wm1 = (const float*)d_in[23]; const float* bm1 = (const float*)d_in[24];
    const float* Wm2 = (const float*)d_in[25]; const float* bm2 = (const float*)d_in[26];
    const float* Wm3 = (const float*)d_in[27]; const float* bm3 = (const float*)d_in[28];
    const float* Wm4 = (const float*)d_in[29]; const float* bm4 = (const float*)d_in[30];
    const float* Wg0 = (const float*)d_in[31]; const float* bg0 = (const float*)d_in[32];
    const float* Wg1 = (const float*)d_in[33]; const float* bg1 = (const float*)d_in[34];
    float* out = (float*)d_out;

    // workspace carve (float units = 4B); fp16 buffers 16B-aligned, padded rows
    float* ws = (float*)d_ws;
    size_t o = 0;
    _Float16* xl  = (_Float16*)(ws + o); o += (size_t)NNP * 4096 / 2;
    _Float16* xr  = (_Float16*)(ws + o); o += (size_t)NNP * 4096 / 2;
    _Float16* x1  = (_Float16*)(ws + o); o += (size_t)NNP * 1024 / 2;
    _Float16* x2  = (_Float16*)(ws + o); o += (size_t)NNP * 512 / 2;
    _Float16* x3  = (_Float16*)(ws + o); o += (size_t)NNP * 256 / 2;
    _Float16* a0p = (_Float16*)(ws + o); o += (size_t)NNP * 1536 / 2;
    _Float16* wb0 = (_Float16*)(ws + o); o += (size_t)1536 * 4096 / 2;
    int* srcA    = (int*)(ws + o); o += NEE;
    int* dstA    = (int*)(ws + o); o += NEE;
    int* cnt     = (int*)(ws + o); o += NN;
    int* eoff    = (int*)(ws + o); o += NN + 1;
    int* cur     = (int*)(ws + o); o += NN;
    int* slist   = (int*)(ws + o); o += NEE;
    float* g     = ws + o; o += NN;
    int* gstart  = (int*)(ws + o); o += NG;
    int* gend    = (int*)(ws + o); o += NG;
    float* gm    = ws + o; o += NG;
    float* ginv  = ws + o; o += NG;
    float* hpool = ws + o; o += NG * 256;

    // build CSR by dst (slist holds src node ids)
    int ebB = (NEE + 255) / 256;
    k_build_edges<<<ebB, 256, 0, stream>>>(ei, srcA, dstA);
    k_zero32<<<(NN + 255) / 256, 256, 0, stream>>>((unsigned int*)cnt, NN);
    k_count<<<ebB, 256, 0, stream>>>(dstA, cnt);
    k_scan<<<1, 256, 0, stream>>>(cnt, eoff, cur);
    k_fill<<<ebB, 256, 0, stream>>>(srcA, dstA, cur, slist);

    // layer-1 input -> fp16 (only conversion needed; later layers emit fp16)
    int nA = NN * 1536;
    k_cvtA<<<(nA + 255) / 256, 256, 0, stream>>>(x, a0p, nA);

    // three GATv2 layers
    run_gat_layer(a0p, 1536, 1024, Wl1, bl1, Wr1, br1, att1, b1,
                  wb0, xl, xr, eoff, slist, x1, stream);
    run_gat_layer(x1,  1024, 512,  Wl2, bl2, Wr2, br2, att2, b2,
                  wb0, xl, xr, eoff, slist, x2, stream);
    run_gat_layer(x2,  512,  256,  Wl3, bl3, Wr3, br3, att3, b3,
                  wb0, xl, xr, eoff, slist, x3, stream);

    // gate + pool + MLP
    k_gate<<<NN, 128, 0, stream>>>(x3, Wg0, bg0, Wg1, bg1, g);
    k_zero32<<<1, 64, 0, stream>>>((unsigned int*)gstart, 2 * NG);
    k_group_bounds<<<(NN + 255) / 256, 256, 0, stream>>>(batch, gstart, gend);
    k_pool_stats<<<NG, 256, 0, stream>>>(g, gstart, gend, gm, ginv);
    k_zero32<<<(NG * 256 + 255) / 256, 256, 0, stream>>>((unsigned int*)hpool, NG * 256);
    k_pool_acc<<<(NN + PCH - 1) / PCH, 256, 0, stream>>>(x3, g, batch, gm, ginv, hpool);
    k_mlp<<<1, 256, 0, stream>>>(hpool, Wm0, bm0, Wm1, bm1, Wm2, bm2,
                                 Wm3, bm3, Wm4, bm4, out);
}